// Round 2
// baseline (110.716 us; speedup 1.0000x reference)
//
#include <hip/hip_runtime.h>

#define BATCH 4
#define SEQ   2048
#define EMB   128
#define NH    16
#define DK    8

// log2(e) / sqrt(8): fold softmax temperature into exp2 (pre-multiplied into qf)
#define QSCALE 0.510069726f

typedef _Float16 v4h  __attribute__((ext_vector_type(4)));
typedef _Float16 v8h  __attribute__((ext_vector_type(8)));
typedef __fp16   v2fp __attribute__((ext_vector_type(2)));
typedef float    v4f  __attribute__((ext_vector_type(4)));
typedef float    v16f __attribute__((ext_vector_type(16)));

#define CHUNK  512
#define NCH    (SEQ / CHUNK)   // 4
#define VTP    520             // VT col pitch (f16): 260 dwords %32 = 4 -> 2-way max

// ---------------------------------------------------------------------------
// R17: packed-f16 exp2. R16's occupancy experiment (2x waves, +0% perf,
// VALUBusy flat at 52%) proved the kernel is NOT latency-bound; model that
// fits all counters: v_exp_f32 issues at ~4 lanes/cyc/SIMD (1/8 rate), so
// the 16-exp burst per kb-iter (~256 issue cyc) is ~2/3 of runtime.
// Fix: softmax exp2 entirely in FULL-RATE packed f16 VALU (2 elem/instr):
//   t = pkrtz(s0,s1)                  (RTZ; |t| <= 4.08, QSCALE folded in qf)
//   m = t + 1536 (RNE in f16)  -> n = m - 1536 exact, f = t - n exact [-.5,.5]
//   p = deg-3 poly(f)                 (3 v_pk_fma_f16, rel err ~1e-4)
//   2^n from bits: (bits16(m)=0x6600+n, n in [-4,4]) ->
//       scale_pair = (bits32(m) - 0x65F165F1) << 10   (2 scalar u32 ops;
//       no inter-half borrow: low half >= 0x65FC; no spill: (15+n)<<10 < 2^15)
//   r = p * scale
// 10 instrs/pair @ 2cyc vs (2 exp @16 + pkrtz @2) = 34cyc: 1.7x on the
// dominant term. Key-split reverted (occupancy proven non-binding).
//
// Structure (R15, HW-verified layouts): block = 4 waves; wave owns 32 q-rows;
// grid 64 bh x 16 = 1024 blocks. S^T = mfma_32x32x16(A=K, B=Q^T); C/D layout
// col=L&31, row=(reg&3)+8(reg>>2)+4(L>>5). P packs in natural reg order into
// the PV B-frag PROVIDED V^T is stored with key-index bits 2<->3 swapped.
// qf=0 on half1 kills k=8..15 padding. Ones-row d=8 of V^T = denominator.
// ---------------------------------------------------------------------------

static __device__ __forceinline__ v2fp exp2_pk2(float a, float b,
    v2fp MAG, v2fp C3, v2fp C2, v2fp C1, v2fp C0) {
  v2fp t = __builtin_amdgcn_cvt_pkrtz(a, b);
  v2fp m = t + MAG;
  asm("" : "+v"(m));            // opacify: block (t+MAG)-MAG folding
  v2fp n = m - MAG;             // exact: round-to-int of t
  v2fp f = t - n;               // exact (Sterbenz), in [-0.5, 0.5]
  v2fp p = f * C3 + C2;
  p = f * p + C1;
  p = f * p + C0;
  unsigned mb;
  __builtin_memcpy(&mb, &m, 4);
  unsigned scb = (mb - 0x65F165F1u) << 10;   // packed f16 bits of 2^n (both halves)
  v2fp sc;
  __builtin_memcpy(&sc, &scb, 4);
  return p * sc;
}

__launch_bounds__(256, 4)
__global__ void attn_kernel(const float* __restrict__ x,
                            const float* __restrict__ theta,
                            _Float16* __restrict__ Ah /* [B*S][128] f16 */) {
  __shared__ __align__(16) _Float16 Kl[CHUNK * 8];   // 8 KB: [key][8 dims]
  __shared__ __align__(16) _Float16 VT[10][VTP];     // 10.2 KB: d 0-7, 8=ones, 9=junk

  const int tid = threadIdx.x;
  const int L   = tid & 63;
  const int ln  = L & 31;
  const int hf  = L >> 5;           // lane half
  const int wv  = tid >> 6;         // wave 0..3
  const int bh     = blockIdx.x >> 4;
  const int qchunk = blockIdx.x & 15;
  const int qb     = qchunk * 128 + wv * 32;   // wave's 32 q rows
  const int b = bh >> 4;
  const int h = bh & 15;

  float th[DK];
#pragma unroll
  for (int i = 0; i < DK; ++i) th[i] = theta[i];

  // packed-f16 exp2 constants (deg-3 minimax-economized for 2^f, f in [-.5,.5])
#define H2(c) ((_Float16)(c))
  const v2fp MAG = {H2(1536.0f), H2(1536.0f)};
  const v2fp C3  = {H2(0.0559208f), H2(0.0559208f)};
  const v2fp C2  = {H2(0.2426315f), H2(0.2426315f)};
  const v2fp C1  = {H2(0.6931210f), H2(0.6931210f)};
  const v2fp C0  = {H2(1.0f), H2(1.0f)};

  // VT row 8 = ones (denominator; persists across restages), row 9 = 0
  for (int i = tid; i < VTP; i += 256) {
    VT[8][i] = (_Float16)1.0f;
    VT[9][i] = (_Float16)0.0f;
  }

  const int c0 = qchunk >> 2;       // 512-chunk containing this block's q rows
  const int mrow = (ln < 9) ? ln : 9;   // clamped VT row for PV A-frag
  const float* xb = x + (size_t)b * SEQ * EMB + h * DK;

  float4 pa0, pa1, pb0, pb1;        // prefetched x rows (keys tid, tid+256)
  {
    const float* xp = xb + (size_t)(c0 * CHUNK + tid) * EMB;
    pa0 = *(const float4*)(xp);
    pa1 = *(const float4*)(xp + 4);
    pb0 = *(const float4*)(xp + 256 * EMB);
    pb1 = *(const float4*)(xp + 256 * EMB + 4);
  }

  v8h qf = {0, 0, 0, 0, 0, 0, 0, 0};
  v16f acc;
#pragma unroll
  for (int i = 0; i < 16; ++i) acc[i] = 0.f;
  v16f zf;
#pragma unroll
  for (int i = 0; i < 16; ++i) zf[i] = 0.f;

  for (int cc = 0; cc < NCH; ++cc) {
    if (cc) __syncthreads();

    // ---- stage: features for keys tid, tid+256 (16 B/lane Kl writes) ----
    {
      float r0[8], r1[8];
      r0[0] = __cosf(pa0.x + th[0]);
      r0[1] = r0[0] * __cosf(pa0.y + th[1]);
      r0[2] = r0[1] * __cosf(pa0.z + th[2]);
      r0[3] = r0[2] * __cosf(pa0.w + th[3]);
      r0[4] = r0[3] * __cosf(pa1.x + th[4]);
      r0[5] = r0[4] * __cosf(pa1.y + th[5]);
      r0[6] = r0[5] * __cosf(pa1.z + th[6]);
      r0[7] = r0[6] * __cosf(pa1.w + th[7]);
      r1[0] = __cosf(pb0.x + th[0]);
      r1[1] = r1[0] * __cosf(pb0.y + th[1]);
      r1[2] = r1[1] * __cosf(pb0.z + th[2]);
      r1[3] = r1[2] * __cosf(pb0.w + th[3]);
      r1[4] = r1[3] * __cosf(pb1.x + th[4]);
      r1[5] = r1[4] * __cosf(pb1.y + th[5]);
      r1[6] = r1[5] * __cosf(pb1.z + th[6]);
      r1[7] = r1[6] * __cosf(pb1.w + th[7]);

      _Float16 h0[8], h1[8];
#pragma unroll
      for (int i = 0; i < 8; ++i) { h0[i] = (_Float16)r0[i]; h1[i] = (_Float16)r1[i]; }

      union { v4h v[2]; float4 f; } u0, u1;
      u0.v[0] = (v4h){h0[0], h0[1], h0[2], h0[3]};
      u0.v[1] = (v4h){h0[4], h0[5], h0[6], h0[7]};
      u1.v[0] = (v4h){h1[0], h1[1], h1[2], h1[3]};
      u1.v[1] = (v4h){h1[4], h1[5], h1[6], h1[7]};
      *(float4*)&Kl[tid * 8]         = u0.f;
      *(float4*)&Kl[(tid + 256) * 8] = u1.f;

      // VT with within-16 slot perm (swap bits 2<->3 of key index)
      const int j0 = tid, j1 = tid + 256;
      const int col0 = (j0 & ~15) | (j0 & 3) | ((j0 & 4) << 1) | ((j0 & 8) >> 1);
      const int col1 = (j1 & ~15) | (j1 & 3) | ((j1 & 4) << 1) | ((j1 & 8) >> 1);
#pragma unroll
      for (int d = 0; d < 8; ++d) {
        VT[d][col0] = h0[d];
        VT[d][col1] = h1[d];
      }
    }
    __syncthreads();

    // prefetch next chunk's x rows (consumed after the compute phase)
    if (cc + 1 < NCH) {
      const int cn = (c0 + cc + 1) & (NCH - 1);
      const float* xp = xb + (size_t)(cn * CHUNK + tid) * EMB;
      pa0 = *(const float4*)(xp);
      pa1 = *(const float4*)(xp + 4);
      pb0 = *(const float4*)(xp + 256 * EMB);
      pb1 = *(const float4*)(xp + 256 * EMB + 4);
    }

    // qf from Kl on the q-containing chunk (visited first); half1 stays 0
    if (cc == 0 && hf == 0) {
      const int ql = (qchunk & 3) * 128 + wv * 32 + ln;
      v8h qv = *(const v8h*)&Kl[ql * 8];
      const _Float16 qs = (_Float16)QSCALE;
      const v8h qsc = {qs, qs, qs, qs, qs, qs, qs, qs};
      qf = qv * qsc;
    }

    // ---- compute: 16 32-key blocks, software-pipelined ----
    v8h kf_next = *(const v8h*)&Kl[ln * 8];   // kb = 0
#pragma unroll 2
    for (int kb = 0; kb < CHUNK / 32; ++kb) {
      const v8h kf = kf_next;
      // issue the S-mfma first, then prefetch next kf + this kb's vt while
      // the mfma runs; the packed-f16 exp block follows on the VALU pipe
      const v16f s = __builtin_amdgcn_mfma_f32_32x32x16_f16(kf, qf, zf, 0, 0, 0);
      if (kb + 1 < CHUNK / 32)
        kf_next = *(const v8h*)&Kl[((kb + 1) * 32 + ln) * 8];
      const v8h vt0 = *(const v8h*)&VT[mrow][kb * 32 + hf * 8];
      const v8h vt1 = *(const v8h*)&VT[mrow][kb * 32 + 16 + hf * 8];
      union { v2fp p[4]; v8h v; } p0, p1;
#pragma unroll
      for (int i = 0; i < 4; ++i) {
        p0.p[i] = exp2_pk2(s[2 * i],     s[2 * i + 1], MAG, C3, C2, C1, C0);
        p1.p[i] = exp2_pk2(s[8 + 2 * i], s[8 + 2 * i + 1], MAG, C3, C2, C1, C0);
      }
      acc = __builtin_amdgcn_mfma_f32_32x32x16_f16(vt0, p0.v, acc, 0, 0, 0);
      acc = __builtin_amdgcn_mfma_f32_32x32x16_f16(vt1, p1.v, acc, 0, 0, 0);
    }
  }

  // ---- epilogue ----
  // acc C-layout: col=q=L&31, row=(reg&3)+8(reg>>2)+4*hf.
  // half0 regs 0-3 = dims 0-3, reg4 = row 8 = den; half1 regs 0-3 = dims 4-7.
  {
    const float den = __shfl(acc[4], ln, 64);   // from half0 lane ln
    const float inv = 1.0f / den;
    const int qrow = qb + ln;
    v4h o = {(_Float16)(acc[0] * inv), (_Float16)(acc[1] * inv),
             (_Float16)(acc[2] * inv), (_Float16)(acc[3] * inv)};
    *(v4h*)(Ah + ((size_t)b * SEQ + qrow) * EMB + h * DK + hf * 4) = o;
  }
}

// ---------------------------------------------------------------------------
// MFMA projection (unchanged from R10-R15). out = Ah · W^T, fp32 out.
// W converted f32->f16 during LDS staging; W row-major IS the B-fragment
// source. Block: 64 rows x 64 cols (grid 128x2), LDS 35 KB, 4 blocks/CU.
// ---------------------------------------------------------------------------
__launch_bounds__(256, 4)
__global__ void proj_kernel(const _Float16* __restrict__ Ah,
                            const float* __restrict__ W,
                            float* __restrict__ out) {
  __shared__ __align__(16) _Float16 Ahs[64][136];
  __shared__ __align__(16) _Float16 Whs[64][136];

  const int tid  = threadIdx.x;
  const int L    = tid & 63;
  const int wv   = tid >> 6;
  const int quad = L >> 4;
  const int ln   = L & 15;
  const int rowbase = blockIdx.x * 64;
  const int colbase = blockIdx.y * 64;

#pragma unroll
  for (int it = 0; it < 4; ++it) {
    const int idx = it * 256 + tid;
    const int r  = idx >> 4;
    const int c8 = idx & 15;
    *(uint4*)&Ahs[r][c8 * 8] =
        *(const uint4*)(Ah + (size_t)(rowbase + r) * EMB + c8 * 8);
  }
#pragma unroll
  for (int it = 0; it < 8; ++it) {
    const int idx = it * 256 + tid;
    const int n  = idx >> 5;
    const int c4 = idx & 31;
    const float4 w = *(const float4*)(W + (size_t)(colbase + n) * EMB + c4 * 4);
    v4h wh = {(_Float16)w.x, (_Float16)w.y, (_Float16)w.z, (_Float16)w.w};
    *(v4h*)&Whs[n][c4 * 4] = wh;
  }
  __syncthreads();

  v4f acc[4];
#pragma unroll
  for (int nt = 0; nt < 4; ++nt) acc[nt] = (v4f){0.f, 0.f, 0.f, 0.f};

#pragma unroll
  for (int k8 = 0; k8 < 8; ++k8) {
    const v4h af = *(const v4h*)&Ahs[wv * 16 + ln][k8 * 16 + quad * 4];
#pragma unroll
    for (int nt = 0; nt < 4; ++nt) {
      const v4h bf = *(const v4h*)&Whs[nt * 16 + ln][k8 * 16 + quad * 4];
      acc[nt] = __builtin_amdgcn_mfma_f32_16x16x16f16(af, bf, acc[nt], 0, 0, 0);
    }
  }

#pragma unroll
  for (int nt = 0; nt < 4; ++nt) {
    const int col = colbase + nt * 16 + ln;
#pragma unroll
    for (int r = 0; r < 4; ++r) {
      out[(size_t)(rowbase + wv * 16 + quad * 4 + r) * EMB + col] = acc[nt][r];
    }
  }
}

// ---------------------------------------------------------------------------
extern "C" void kernel_launch(void* const* d_in, const int* in_sizes, int n_in,
                              void* d_out, int out_size, void* d_ws, size_t ws_size,
                              hipStream_t stream) {
  const float* x     = (const float*)d_in[0];  // [4,2048,128]
  const float* theta = (const float*)d_in[1];  // [8]
  const float* w_out = (const float*)d_in[2];  // [128,128]
  float* out = (float*)d_out;                  // [4,2048,128]

  _Float16* Ah = (_Float16*)d_ws;              // [8192][128] f16 = 2 MB

  // fused features + attention: 64 bh x 16 q-chunks = 1024 blocks, 4 waves
  attn_kernel<<<dim3(1024), dim3(256), 0, stream>>>(x, theta, Ah);

  // projection: 128 row-tiles x 2 col-tiles
  proj_kernel<<<dim3((BATCH * SEQ) / 64, 2), dim3(256), 0, stream>>>(Ah, w_out, out);
}

// Round 3
// 94.001 us; speedup vs baseline: 1.1778x; 1.1778x over previous
//
#include <hip/hip_runtime.h>

#define BATCH 4
#define SEQ   2048
#define EMB   128
#define NH    16
#define DK    8

// log2(e) / sqrt(8): fold softmax temperature into exp2 (pre-multiplied into qf)
#define QSCALE 0.510069726f

typedef _Float16 v4h  __attribute__((ext_vector_type(4)));
typedef _Float16 v8h  __attribute__((ext_vector_type(8)));
typedef __fp16   v2fp __attribute__((ext_vector_type(2)));
typedef float    v4f  __attribute__((ext_vector_type(4)));
typedef float    v16f __attribute__((ext_vector_type(16)));

#define CHUNK  512
#define NCH    (SEQ / CHUNK)   // 4
#define VTP    520             // VT col pitch (f16): 260 dwords %32 = 4 -> 2-way max

// ---------------------------------------------------------------------------
// R18: R15 core + explicit 1-deep S-skew software pipeline.
// Evidence trail: R16 (2x waves, but launch_bounds(256,8) squeezed VGPR to 32)
// = flat; R17 (exp2 on packed VALU) = +18us while removing exps saved ~0
// => trans pipe NOT the limiter; exps were hidden. R15's VGPR=44 shows the
// compiler kept ONE live S-tile: every iter stalls on S-mfma latency before
// the exp burst, and the exp->pack->PV chain runs un-overlapped. Fix at
// source level: compute S(kb+1) BEFORE consuming s(kb); prefetch kf 2-deep.
// Per-iter producer-consumer distance = one full iteration (~390 cyc) for
// both the MFMA result and the kf ds_read; vt->PV0 covered by the 8-exp
// burst. Costs 2 live S-tiles (+~50 VGPR), fine under the (256,4) cap of
// 128 at the grid-limited 4 blocks/CU.
//
// Structure (R15, HW-verified layouts): block = 4 waves; wave owns 32 q-rows;
// grid 64 bh x 16 = 1024 blocks. S^T = mfma_32x32x16(A=K, B=Q^T); C/D layout
// col=L&31, row=(reg&3)+8(reg>>2)+4(L>>5). P=exp2(S^T) packs with pkrtz in
// natural reg order into the PV B-frag PROVIDED V^T is stored with key-index
// bits 2<->3 swapped. qf=0 on half1 kills the k=8..15 padding. Ones-row d=8
// of V^T gives the softmax denominator; out rows 9..31 garbage, never stored.
// Plain-exp softmax exact: |score*log2e/sqrt8| <= 4.1 (features <= 1).
// ---------------------------------------------------------------------------
__launch_bounds__(256, 4)
__global__ void attn_kernel(const float* __restrict__ x,
                            const float* __restrict__ theta,
                            _Float16* __restrict__ Ah /* [B*S][128] f16 */) {
  __shared__ __align__(16) _Float16 Kl[CHUNK * 8];   // 8 KB: [key][8 dims]
  __shared__ __align__(16) _Float16 VT[10][VTP];     // 10.2 KB: d 0-7, 8=ones, 9=junk

  const int tid = threadIdx.x;
  const int L   = tid & 63;
  const int ln  = L & 31;
  const int hf  = L >> 5;           // lane half
  const int wv  = tid >> 6;         // wave 0..3
  const int bh     = blockIdx.x >> 4;
  const int qchunk = blockIdx.x & 15;
  const int qb     = qchunk * 128 + wv * 32;   // wave's 32 q rows
  const int b = bh >> 4;
  const int h = bh & 15;

  float th[DK];
#pragma unroll
  for (int i = 0; i < DK; ++i) th[i] = theta[i];

  // VT row 8 = ones (denominator; persists across restages), row 9 = 0
  for (int i = tid; i < VTP; i += 256) {
    VT[8][i] = (_Float16)1.0f;
    VT[9][i] = (_Float16)0.0f;
  }

  const int c0 = qchunk >> 2;       // 512-chunk containing this block's q rows
  const int mrow = (ln < 9) ? ln : 9;   // clamped VT row for PV A-frag
  const float* xb = x + (size_t)b * SEQ * EMB + h * DK;

  float4 pa0, pa1, pb0, pb1;        // prefetched x rows (keys tid, tid+256)
  {
    const float* xp = xb + (size_t)(c0 * CHUNK + tid) * EMB;
    pa0 = *(const float4*)(xp);
    pa1 = *(const float4*)(xp + 4);
    pb0 = *(const float4*)(xp + 256 * EMB);
    pb1 = *(const float4*)(xp + 256 * EMB + 4);
  }

  v8h qf = {0, 0, 0, 0, 0, 0, 0, 0};
  v16f acc;
#pragma unroll
  for (int i = 0; i < 16; ++i) acc[i] = 0.f;
  v16f zf;
#pragma unroll
  for (int i = 0; i < 16; ++i) zf[i] = 0.f;

  for (int cc = 0; cc < NCH; ++cc) {
    if (cc) __syncthreads();

    // ---- stage: features for keys tid, tid+256 (16 B/lane Kl writes) ----
    {
      float r0[8], r1[8];
      r0[0] = __cosf(pa0.x + th[0]);
      r0[1] = r0[0] * __cosf(pa0.y + th[1]);
      r0[2] = r0[1] * __cosf(pa0.z + th[2]);
      r0[3] = r0[2] * __cosf(pa0.w + th[3]);
      r0[4] = r0[3] * __cosf(pa1.x + th[4]);
      r0[5] = r0[4] * __cosf(pa1.y + th[5]);
      r0[6] = r0[5] * __cosf(pa1.z + th[6]);
      r0[7] = r0[6] * __cosf(pa1.w + th[7]);
      r1[0] = __cosf(pb0.x + th[0]);
      r1[1] = r1[0] * __cosf(pb0.y + th[1]);
      r1[2] = r1[1] * __cosf(pb0.z + th[2]);
      r1[3] = r1[2] * __cosf(pb0.w + th[3]);
      r1[4] = r1[3] * __cosf(pb1.x + th[4]);
      r1[5] = r1[4] * __cosf(pb1.y + th[5]);
      r1[6] = r1[5] * __cosf(pb1.z + th[6]);
      r1[7] = r1[6] * __cosf(pb1.w + th[7]);

      _Float16 h0[8], h1[8];
#pragma unroll
      for (int i = 0; i < 8; ++i) { h0[i] = (_Float16)r0[i]; h1[i] = (_Float16)r1[i]; }

      union { v4h v[2]; float4 f; } u0, u1;
      u0.v[0] = (v4h){h0[0], h0[1], h0[2], h0[3]};
      u0.v[1] = (v4h){h0[4], h0[5], h0[6], h0[7]};
      u1.v[0] = (v4h){h1[0], h1[1], h1[2], h1[3]};
      u1.v[1] = (v4h){h1[4], h1[5], h1[6], h1[7]};
      *(float4*)&Kl[tid * 8]         = u0.f;
      *(float4*)&Kl[(tid + 256) * 8] = u1.f;

      // VT with within-16 slot perm (swap bits 2<->3 of key index)
      const int j0 = tid, j1 = tid + 256;
      const int col0 = (j0 & ~15) | (j0 & 3) | ((j0 & 4) << 1) | ((j0 & 8) >> 1);
      const int col1 = (j1 & ~15) | (j1 & 3) | ((j1 & 4) << 1) | ((j1 & 8) >> 1);
#pragma unroll
      for (int d = 0; d < 8; ++d) {
        VT[d][col0] = h0[d];
        VT[d][col1] = h1[d];
      }
    }
    __syncthreads();

    // prefetch next chunk's x rows (consumed after the compute phase)
    if (cc + 1 < NCH) {
      const int cn = (c0 + cc + 1) & (NCH - 1);
      const float* xp = xb + (size_t)(cn * CHUNK + tid) * EMB;
      pa0 = *(const float4*)(xp);
      pa1 = *(const float4*)(xp + 4);
      pb0 = *(const float4*)(xp + 256 * EMB);
      pb1 = *(const float4*)(xp + 256 * EMB + 4);
    }

    // qf from Kl on the q-containing chunk (visited first); half1 stays 0
    if (cc == 0 && hf == 0) {
      const int ql = (qchunk & 3) * 128 + wv * 32 + ln;
      v8h qv = *(const v8h*)&Kl[ql * 8];
      const _Float16 qs = (_Float16)QSCALE;
      const v8h qsc = {qs, qs, qs, qs, qs, qs, qs, qs};
      qf = qv * qsc;
    }

    // ---- compute: 16 32-key tiles, 1-deep S-skew pipeline ----
    // state entering iter kb: s_cur = S(kb) (computed one full iter ago),
    // kf_a = K-tile(kb+1) (loaded one iter ago). No same-iter RAW stalls.
    v8h kf_a = *(const v8h*)&Kl[ln * 8];                    // K-tile 0
    v16f s_cur = __builtin_amdgcn_mfma_f32_32x32x16_f16(kf_a, qf, zf, 0, 0, 0);
    kf_a = *(const v8h*)&Kl[(32 + ln) * 8];                 // K-tile 1

#pragma unroll 5
    for (int kb = 0; kb < 15; ++kb) {
      // 2-deep kf prefetch ((kb+2)&15 wraps harmlessly to tile 0 at kb=14)
      const v8h kf_b = *(const v8h*)&Kl[((((kb + 2) & 15) * 32) + ln) * 8];
      // issue S(kb+1) now; its result is consumed NEXT iteration
      const v16f s_next = __builtin_amdgcn_mfma_f32_32x32x16_f16(kf_a, qf, zf, 0, 0, 0);
      const v8h vt0 = *(const v8h*)&VT[mrow][kb * 32 + hf * 8];
      const v8h vt1 = *(const v8h*)&VT[mrow][kb * 32 + 16 + hf * 8];
      union { v2fp p[4]; v8h v; } p0, p1;
#pragma unroll
      for (int i = 0; i < 4; ++i) {
        p0.p[i] = __builtin_amdgcn_cvt_pkrtz(
            __builtin_amdgcn_exp2f(s_cur[2 * i]),
            __builtin_amdgcn_exp2f(s_cur[2 * i + 1]));
      }
      acc = __builtin_amdgcn_mfma_f32_32x32x16_f16(vt0, p0.v, acc, 0, 0, 0);
      // p1's exps overlap PV0's matrix-pipe time
#pragma unroll
      for (int i = 0; i < 4; ++i) {
        p1.p[i] = __builtin_amdgcn_cvt_pkrtz(
            __builtin_amdgcn_exp2f(s_cur[8 + 2 * i]),
            __builtin_amdgcn_exp2f(s_cur[8 + 2 * i + 1]));
      }
      acc = __builtin_amdgcn_mfma_f32_32x32x16_f16(vt1, p1.v, acc, 0, 0, 0);
      s_cur = s_next;
      kf_a  = kf_b;
    }
    // peeled kb=15: consume s_cur, no s_next
    {
      const int kb = 15;
      const v8h vt0 = *(const v8h*)&VT[mrow][kb * 32 + hf * 8];
      const v8h vt1 = *(const v8h*)&VT[mrow][kb * 32 + 16 + hf * 8];
      union { v2fp p[4]; v8h v; } p0, p1;
#pragma unroll
      for (int i = 0; i < 4; ++i) {
        p0.p[i] = __builtin_amdgcn_cvt_pkrtz(
            __builtin_amdgcn_exp2f(s_cur[2 * i]),
            __builtin_amdgcn_exp2f(s_cur[2 * i + 1]));
        p1.p[i] = __builtin_amdgcn_cvt_pkrtz(
            __builtin_amdgcn_exp2f(s_cur[8 + 2 * i]),
            __builtin_amdgcn_exp2f(s_cur[8 + 2 * i + 1]));
      }
      acc = __builtin_amdgcn_mfma_f32_32x32x16_f16(vt0, p0.v, acc, 0, 0, 0);
      acc = __builtin_amdgcn_mfma_f32_32x32x16_f16(vt1, p1.v, acc, 0, 0, 0);
    }
  }

  // ---- epilogue ----
  // acc C-layout: col=q=L&31, row=(reg&3)+8(reg>>2)+4*hf.
  // half0 regs 0-3 = dims 0-3, reg4 = row 8 = den; half1 regs 0-3 = dims 4-7.
  {
    const float den = __shfl(acc[4], ln, 64);   // from half0 lane ln
    const float inv = 1.0f / den;
    const int qrow = qb + ln;
    v4h o = {(_Float16)(acc[0] * inv), (_Float16)(acc[1] * inv),
             (_Float16)(acc[2] * inv), (_Float16)(acc[3] * inv)};
    *(v4h*)(Ah + ((size_t)b * SEQ + qrow) * EMB + h * DK + hf * 4) = o;
  }
}

// ---------------------------------------------------------------------------
// MFMA projection (unchanged from R10-R15). out = Ah · W^T, fp32 out.
// W converted f32->f16 during LDS staging; W row-major IS the B-fragment
// source. Block: 64 rows x 64 cols (grid 128x2), LDS 35 KB, 4 blocks/CU.
// ---------------------------------------------------------------------------
__launch_bounds__(256, 4)
__global__ void proj_kernel(const _Float16* __restrict__ Ah,
                            const float* __restrict__ W,
                            float* __restrict__ out) {
  __shared__ __align__(16) _Float16 Ahs[64][136];
  __shared__ __align__(16) _Float16 Whs[64][136];

  const int tid  = threadIdx.x;
  const int L    = tid & 63;
  const int wv   = tid >> 6;
  const int quad = L >> 4;
  const int ln   = L & 15;
  const int rowbase = blockIdx.x * 64;
  const int colbase = blockIdx.y * 64;

#pragma unroll
  for (int it = 0; it < 4; ++it) {
    const int idx = it * 256 + tid;
    const int r  = idx >> 4;
    const int c8 = idx & 15;
    *(uint4*)&Ahs[r][c8 * 8] =
        *(const uint4*)(Ah + (size_t)(rowbase + r) * EMB + c8 * 8);
  }
#pragma unroll
  for (int it = 0; it < 8; ++it) {
    const int idx = it * 256 + tid;
    const int n  = idx >> 5;
    const int c4 = idx & 31;
    const float4 w = *(const float4*)(W + (size_t)(colbase + n) * EMB + c4 * 4);
    v4h wh = {(_Float16)w.x, (_Float16)w.y, (_Float16)w.z, (_Float16)w.w};
    *(v4h*)&Whs[n][c4 * 4] = wh;
  }
  __syncthreads();

  v4f acc[4];
#pragma unroll
  for (int nt = 0; nt < 4; ++nt) acc[nt] = (v4f){0.f, 0.f, 0.f, 0.f};

#pragma unroll
  for (int k8 = 0; k8 < 8; ++k8) {
    const v4h af = *(const v4h*)&Ahs[wv * 16 + ln][k8 * 16 + quad * 4];
#pragma unroll
    for (int nt = 0; nt < 4; ++nt) {
      const v4h bf = *(const v4h*)&Whs[nt * 16 + ln][k8 * 16 + quad * 4];
      acc[nt] = __builtin_amdgcn_mfma_f32_16x16x16f16(af, bf, acc[nt], 0, 0, 0);
    }
  }

#pragma unroll
  for (int nt = 0; nt < 4; ++nt) {
    const int col = colbase + nt * 16 + ln;
#pragma unroll
    for (int r = 0; r < 4; ++r) {
      out[(size_t)(rowbase + wv * 16 + quad * 4 + r) * EMB + col] = acc[nt][r];
    }
  }
}

// ---------------------------------------------------------------------------
extern "C" void kernel_launch(void* const* d_in, const int* in_sizes, int n_in,
                              void* d_out, int out_size, void* d_ws, size_t ws_size,
                              hipStream_t stream) {
  const float* x     = (const float*)d_in[0];  // [4,2048,128]
  const float* theta = (const float*)d_in[1];  // [8]
  const float* w_out = (const float*)d_in[2];  // [128,128]
  float* out = (float*)d_out;                  // [4,2048,128]

  _Float16* Ah = (_Float16*)d_ws;              // [8192][128] f16 = 2 MB

  // fused features + attention: 64 bh x 16 q-chunks = 1024 blocks, 4 waves
  attn_kernel<<<dim3(1024), dim3(256), 0, stream>>>(x, theta, Ah);

  // projection: 128 row-tiles x 2 col-tiles
  proj_kernel<<<dim3((BATCH * SEQ) / 64, 2), dim3(256), 0, stream>>>(Ah, w_out, out);
}